// Round 9
// baseline (403.609 us; speedup 1.0000x reference)
//
#include <hip/hip_runtime.h>
#include <hip/hip_bf16.h>
#include <hip/hip_fp16.h>

// DFAChebNet forward.
//  layer: x@W0 + (agg(x)-x)@W1 + b == x@(W0-W1) + agg(x@W1) + b   (project first)
//  aggregation: CSR pull-gather.
//  R20: CSR build via histogram -> scan -> atomic direct scatter (replaces
//  the partition + per-bucket LDS counting sort):
//   k_zero        : deg/dsum/btot = 0
//   k_hist        : atomicAdd deg[row], dsum[row] (fp32 weights), btot via
//                   LDS-aggregated per-block bucket counts
//   k_rowptr_proj1: per 256-row bucket: btot prefix + wave-scan of deg ->
//                   rowptr & cursor; dinv = rsqrt(dsum); fused proj1 (R18
//                   verbatim: 16 MFMA tiles/block, dinv via LDS)
//   k_scatter     : pos = atomicAdd(cursor[row]); partC[pos] = col|wpack(w)
//  partS (12.8MB W + 12.8MB R) and the 4096-record sort eliminated; CAP
//  overflow hazard gone. Intra-row edge order is atomic-arrival order --
//  same nondeterminism class as the old LDS-cursor sort (absmax stable at
//  0.125 across all prior rounds). Gathers = R19 block-tile 4-chain form.

constexpr int NN   = 100000;
constexpr int NE   = 1600000;
constexpr int FIN  = 128;
constexpr int HID  = 16;
constexpr int NCLS = 32;

constexpr int RB    = 256;                         // rows per bucket
constexpr int NBKT  = (NN + RB - 1) / RB;          // 391
constexpr int EPB   = 4096;                        // edges per block
constexpr int EPT   = EPB / 256;                   // 16 edges per thread
constexpr int GP    = (NE + EPB - 1) / EPB;        // 391
constexpr int NTILE = NN / 16;                     // 6250 tiles (exact)

typedef float f32x2 __attribute__((ext_vector_type(2)));
typedef float f32x4 __attribute__((ext_vector_type(4)));
typedef short bf16x8 __attribute__((ext_vector_type(8)));

#if defined(__has_builtin)
#if __has_builtin(__builtin_amdgcn_cvt_pk_f32_fp8)
#define HAVE_CVT_FP8 1
#endif
#endif

// fp8 e4m3fn encode (RNE, subnormals flushed to 0, clamp at 448)
static __device__ __forceinline__ unsigned int f2e4m3(float f) {
    union { float f; unsigned int u; } v; v.f = f;
    unsigned int s = (v.u >> 24) & 0x80u;
    unsigned int au = v.u & 0x7fffffffu;
    if (au > 0x43E00000u) au = 0x43E00000u;        // clamp to 448
    au += 0x7ffffu + ((au >> 20) & 1u);            // RNE into 3-bit mantissa
    int e4 = (int)(au >> 23) - 120;                // 127-7
    unsigned int m = (au >> 20) & 7u;
    unsigned int byte = (e4 <= 0) ? 0u : (((unsigned int)e4 << 3) | m);
    return s | byte;
}
// 4 packed fp8 -> acc[0..3] += w * val
static __device__ __forceinline__ void fp8x4_fma(unsigned int v, float w, float* acc) {
#ifdef HAVE_CVT_FP8
    f32x2 lo = __builtin_amdgcn_cvt_pk_f32_fp8((int)v, false);
    f32x2 hi = __builtin_amdgcn_cvt_pk_f32_fp8((int)v, true);
    acc[0] += w * lo.x; acc[1] += w * lo.y;
    acc[2] += w * hi.x; acc[3] += w * hi.y;
#else
#pragma unroll
    for (int i = 0; i < 4; i++) {
        unsigned int b = (v >> (8 * i)) & 0xffu;
        float f = __int_as_float((int)(((b & 0x80u) << 24) | ((b & 0x7fu) << 20))) * 0x1p120f;
        acc[i] += w * f;
    }
#endif
}
// bf16 RNE
static __device__ __forceinline__ unsigned short f2bf(float f) {
    union { float f; unsigned int u; } v; v.f = f;
    unsigned int r = v.u + 0x7fffu + ((v.u >> 16) & 1u);
    return (unsigned short)(r >> 16);
}
// edge record: col(17 bits) | w(15 bits = signless bf16, RNE)
static __device__ __forceinline__ unsigned int wpack(float wf) {
    unsigned int b = __float_as_uint(wf) + 0x8000u;
    return (b >> 16) & 0x7fffu;
}
static __device__ __forceinline__ float wdec(unsigned int u) {
    return __uint_as_float((u >> 17) << 16);
}

// ---- zero deg / dsum / btot ----
__global__ void k_zero(int* __restrict__ deg, float* __restrict__ dsum,
                       int* __restrict__ btot) {
    int i = blockIdx.x * blockDim.x + threadIdx.x;
    if (i < NN) { deg[i] = 0; dsum[i] = 0.f; }
    if (i < NBKT) btot[i] = 0;
}

// ---- pass 1: degree + weight-sum histogram (global atomics, L2-resident;
// bucket totals LDS-aggregated per block to cut contention 4096x) ----
__global__ __launch_bounds__(256) void k_hist(
    const int* __restrict__ row, const float* __restrict__ ew,
    int* __restrict__ deg, float* __restrict__ dsum, int* __restrict__ btot) {
    __shared__ int sh_bt[NBKT];
    int tid = threadIdx.x;
    for (int i = tid; i < NBKT; i += 256) sh_bt[i] = 0;
    __syncthreads();
    long e0 = (long)blockIdx.x * EPB;
#pragma unroll
    for (int i = 0; i < EPT; i++) {
        long e = e0 + i * 256 + tid;
        if (e < NE) {
            int r = row[e];
            float w = ew[e];
            atomicAdd(&deg[r], 1);
            atomicAdd(&dsum[r], w);
            atomicAdd(&sh_bt[r >> 8], 1);
        }
    }
    __syncthreads();
    for (int i = tid; i < NBKT; i += 256)
        if (sh_bt[i]) atomicAdd(&btot[i], sh_bt[i]);
}

// ---- pass 2: rowptr (btot prefix + wave-scan of deg) + cursor + dinv,
// then fused proj1 for the block's own 256 rows (R18-verbatim math):
//   xa = x@(W1_0-W1_1)+b1 ; xb8 = fp8(dinv * (x@W1_1))
__global__ __launch_bounds__(256) void k_rowptr_proj1(
    const int* __restrict__ deg, const float* __restrict__ dsum,
    const int* __restrict__ btot,
    int* __restrict__ rowptr, int* __restrict__ cursor,
    float* __restrict__ dinv,
    const float* __restrict__ x, const float* __restrict__ W1_0,
    const float* __restrict__ W1_1, const float* __restrict__ b1,
    float* __restrict__ xa, unsigned char* __restrict__ xb8) {
    __shared__ int wtot[4];
    __shared__ int red[4];
    __shared__ float sh_dinv[RB];
    int b = blockIdx.x;
    int tid = threadIdx.x;
    int lane = tid & 63, wv = tid >> 6;
    // prefix over buckets < b
    int partial = 0;
    for (int i = tid; i < b; i += 256) partial += btot[i];
#pragma unroll
    for (int off = 1; off < 64; off <<= 1) partial += __shfl_xor(partial, off, 64);
    if (lane == 0) red[wv] = partial;
    __syncthreads();
    int start = red[0] + red[1] + red[2] + red[3];
    // local exclusive scan of deg over the block's 256 rows
    int node = b * RB + tid;
    int v = (node < NN) ? deg[node] : 0;
    int sc = v;
#pragma unroll
    for (int off = 1; off < 64; off <<= 1) {
        int up = __shfl_up(sc, off, 64);
        if (lane >= off) sc += up;
    }
    if (lane == 63) wtot[wv] = sc;
    __syncthreads();
    int add = 0;
    for (int w2 = 0; w2 < wv; w2++) add += wtot[w2];
    int ex = sc + add - v;
    if (node < NN) {
        int rp = start + ex;
        rowptr[node] = rp;
        cursor[node] = rp;
        float ds = dsum[node];
        float dv = ds > 0.f ? rsqrtf(ds) : 0.f;
        dinv[node] = dv;
        sh_dinv[tid] = dv;
    } else {
        if (node == NN) rowptr[NN] = start + ex;   // == NE
        sh_dinv[tid] = 0.f;
    }
    __syncthreads();

    // ---- fused proj1 over this block's 16 tiles (4 per wave) ----
    {
        int pcol = lane & 15, quad = lane >> 4;
        bf16x8 bfrag[2][4];
#pragma unroll
        for (int mat = 0; mat < 2; mat++) {
            const float* W = mat ? W1_1 : W1_0;
#pragma unroll
            for (int kb = 0; kb < 4; kb++) {
                bf16x8 f;
#pragma unroll
                for (int j = 0; j < 8; j++)
                    f[j] = (short)f2bf(W[(kb * 32 + quad * 8 + j) * HID + pcol]);
                bfrag[mat][kb] = f;
            }
        }
        float b1v = b1[pcol];
#pragma unroll
        for (int i = 0; i < 4; i++) {
            int tb = wv * 4 + i;
            int wid = b * 16 + tb;
            if (wid >= NTILE) break;
            const float* xrow = x + ((long)wid * 16 + pcol) * FIN + quad * 8;
            float4 xb[8];
#pragma unroll
            for (int kb = 0; kb < 4; kb++) {
                xb[2 * kb]     = *(const float4*)(xrow + kb * 32);
                xb[2 * kb + 1] = *(const float4*)(xrow + kb * 32 + 4);
            }
            f32x4 acc0 = {0.f, 0.f, 0.f, 0.f}, acc1 = {0.f, 0.f, 0.f, 0.f};
#pragma unroll
            for (int kb = 0; kb < 4; kb++) {
                float4 a0 = xb[2 * kb], a1 = xb[2 * kb + 1];
                bf16x8 af;
                af[0] = (short)f2bf(a0.x); af[1] = (short)f2bf(a0.y);
                af[2] = (short)f2bf(a0.z); af[3] = (short)f2bf(a0.w);
                af[4] = (short)f2bf(a1.x); af[5] = (short)f2bf(a1.y);
                af[6] = (short)f2bf(a1.z); af[7] = (short)f2bf(a1.w);
                acc0 = __builtin_amdgcn_mfma_f32_16x16x32_bf16(af, bfrag[0][kb], acc0, 0, 0, 0);
                acc1 = __builtin_amdgcn_mfma_f32_16x16x32_bf16(af, bfrag[1][kb], acc1, 0, 0, 0);
            }
#pragma unroll
            for (int r = 0; r < 4; r++) {
                int lidx = tb * 16 + quad * 4 + r;          // in-block row
                long nd = (long)b * RB + lidx;
                float a0 = acc0[r], a1 = acc1[r];
                xa[nd * HID + pcol] = a0 - a1 + b1v;
                float dn = sh_dinv[lidx];
                xb8[nd * HID + pcol] = (unsigned char)f2e4m3(dn * a1);
            }
        }
    }
}

// ---- pass 3: direct scatter to final CSR position ----
__global__ __launch_bounds__(256) void k_scatter(
    const int* __restrict__ row, const int* __restrict__ col,
    const float* __restrict__ ew,
    int* __restrict__ cursor, unsigned int* __restrict__ partC) {
    int tid = threadIdx.x;
    long e0 = (long)blockIdx.x * EPB;
#pragma unroll
    for (int i = 0; i < EPT; i++) {
        long e = e0 + i * 256 + tid;
        if (e < NE) {
            int r = row[e];
            int c = col[e];
            float w = ew[e];
            int pos = atomicAdd(&cursor[r], 1);
            partC[pos] = (unsigned int)c | (wpack(w) << 17);
        }
    }
}

// Layer-1 gather (block-tile, 4-chain). 1 block = one 16-node tile,
// wave wv owns nodes tile*16 + wv*4 + {0..3}; 4 independent chains/wave.
// h16 = bf16(relu(xa + dn*agg(xb8))), h8 = fp8(dn*h).
// lane = (d = dword 0..3, p = edge parity 0..15).
__global__ __launch_bounds__(256) void k_gather1(
    const int* __restrict__ rowptr, const unsigned int* __restrict__ partC,
    const float* __restrict__ dinv, const unsigned char* __restrict__ xb8,
    const float* __restrict__ xa,
    unsigned short* __restrict__ h16, unsigned char* __restrict__ h8) {
    int tile = blockIdx.x;
    int tid = threadIdx.x;
    int lane = tid & 63, wv = tid >> 6;
    int d = lane & 3, p = lane >> 2;
    int nb = tile * 16 + wv * 4;                 // wave's first node

    int s[5];
#pragma unroll
    for (int k = 0; k < 5; k++) s[k] = rowptr[nb + k];
    float4 dn4 = *(const float4*)(dinv + nb);
    float4 xav[4];
#pragma unroll
    for (int c = 0; c < 4; c++)
        xav[c] = *(const float4*)(xa + (long)(nb + c) * HID + d * 4);

    float acc[4][4];
#pragma unroll
    for (int c = 0; c < 4; c++)
#pragma unroll
        for (int i = 0; i < 4; i++) acc[c][i] = 0.f;

    int j0 = s[0] + p, j1 = s[1] + p, j2 = s[2] + p, j3 = s[3] + p;
    int e0 = s[1], e1 = s[2], e2 = s[3], e3 = s[4];
    while ((j0 < e0) | (j1 < e1) | (j2 < e2) | (j3 < e3)) {
        if (j0 < e0) {
            unsigned int u = partC[j0];
            unsigned int v = *(const unsigned int*)(xb8 + (u & 0x1FFFF) * HID + d * 4);
            fp8x4_fma(v, wdec(u), acc[0]);
            j0 += 16;
        }
        if (j1 < e1) {
            unsigned int u = partC[j1];
            unsigned int v = *(const unsigned int*)(xb8 + (u & 0x1FFFF) * HID + d * 4);
            fp8x4_fma(v, wdec(u), acc[1]);
            j1 += 16;
        }
        if (j2 < e2) {
            unsigned int u = partC[j2];
            unsigned int v = *(const unsigned int*)(xb8 + (u & 0x1FFFF) * HID + d * 4);
            fp8x4_fma(v, wdec(u), acc[2]);
            j2 += 16;
        }
        if (j3 < e3) {
            unsigned int u = partC[j3];
            unsigned int v = *(const unsigned int*)(xb8 + (u & 0x1FFFF) * HID + d * 4);
            fp8x4_fma(v, wdec(u), acc[3]);
            j3 += 16;
        }
    }
#pragma unroll
    for (int i = 0; i < 4; i++) {
#pragma unroll
        for (int c = 0; c < 4; c++) acc[c][i] += __shfl_xor(acc[c][i], 4);
#pragma unroll
        for (int c = 0; c < 4; c++) acc[c][i] += __shfl_xor(acc[c][i], 8);
#pragma unroll
        for (int c = 0; c < 4; c++) acc[c][i] += __shfl_xor(acc[c][i], 16);
#pragma unroll
        for (int c = 0; c < 4; c++) acc[c][i] += __shfl_xor(acc[c][i], 32);
    }
    if (p == 0) {   // lanes 0..3 (lane == d)
        float dnc[4] = {dn4.x, dn4.y, dn4.z, dn4.w};
#pragma unroll
        for (int c = 0; c < 4; c++) {
            long n = nb + c;
            float h0 = fmaxf(xav[c].x + dnc[c] * acc[c][0], 0.f);
            float h1 = fmaxf(xav[c].y + dnc[c] * acc[c][1], 0.f);
            float h2 = fmaxf(xav[c].z + dnc[c] * acc[c][2], 0.f);
            float h3 = fmaxf(xav[c].w + dnc[c] * acc[c][3], 0.f);
            ushort4 u;
            u.x = f2bf(h0); u.y = f2bf(h1); u.z = f2bf(h2); u.w = f2bf(h3);
            *(ushort4*)(h16 + n * HID + d * 4) = u;
            unsigned int pk = f2e4m3(dnc[c] * h0) | (f2e4m3(dnc[c] * h1) << 8)
                            | (f2e4m3(dnc[c] * h2) << 16) | (f2e4m3(dnc[c] * h3) << 24);
            *(unsigned int*)(h8 + n * HID + d * 4) = pk;
        }
    }
}

// Layer-2 gather + final projection + log-softmax (R18-verbatim).
//  1 block = one 16-node tile. 4 waves x 4-chain interleaved gather:
//  wave wv owns nodes tile*16 + wv*4 + {0..3}; g = bf16(dn*agg(h8)) goes to
//  512B LDS. Then wave 0: v = [h16;g]@[W2_0-W2_1;W2_1] + b2 (two 16x16x32
//  bf16 MFMAs, K=32 concat) and log-softmax.
__global__ __launch_bounds__(256) void k_gather2_lsm(
    const int* __restrict__ rowptr, const unsigned int* __restrict__ partC,
    const float* __restrict__ dinv, const unsigned char* __restrict__ h8,
    const unsigned short* __restrict__ h16,
    const float* __restrict__ W2_0, const float* __restrict__ W2_1,
    const float* __restrict__ b2, float* __restrict__ out) {
    __shared__ unsigned short sh_g[16][16];     // bf16 g for the tile
    int tile = blockIdx.x;
    int tid = threadIdx.x;
    int lane = tid & 63, wv = tid >> 6;
    int d = lane & 3, p = lane >> 2;
    int nb = tile * 16 + wv * 4;                 // wave's first node

    int s[5];
#pragma unroll
    for (int k = 0; k < 5; k++) s[k] = rowptr[nb + k];
    float4 dn4 = *(const float4*)(dinv + nb);

    float acc[4][4];
#pragma unroll
    for (int c = 0; c < 4; c++)
#pragma unroll
        for (int i = 0; i < 4; i++) acc[c][i] = 0.f;

    int j0 = s[0] + p, j1 = s[1] + p, j2 = s[2] + p, j3 = s[3] + p;
    int e0 = s[1], e1 = s[2], e2 = s[3], e3 = s[4];
    while ((j0 < e0) | (j1 < e1) | (j2 < e2) | (j3 < e3)) {
        if (j0 < e0) {
            unsigned int u = partC[j0];
            unsigned int v = *(const unsigned int*)(h8 + (u & 0x1FFFF) * HID + d * 4);
            fp8x4_fma(v, wdec(u), acc[0]);
            j0 += 16;
        }
        if (j1 < e1) {
            unsigned int u = partC[j1];
            unsigned int v = *(const unsigned int*)(h8 + (u & 0x1FFFF) * HID + d * 4);
            fp8x4_fma(v, wdec(u), acc[1]);
            j1 += 16;
        }
        if (j2 < e2) {
            unsigned int u = partC[j2];
            unsigned int v = *(const unsigned int*)(h8 + (u & 0x1FFFF) * HID + d * 4);
            fp8x4_fma(v, wdec(u), acc[2]);
            j2 += 16;
        }
        if (j3 < e3) {
            unsigned int u = partC[j3];
            unsigned int v = *(const unsigned int*)(h8 + (u & 0x1FFFF) * HID + d * 4);
            fp8x4_fma(v, wdec(u), acc[3]);
            j3 += 16;
        }
    }
#pragma unroll
    for (int i = 0; i < 4; i++) {
        acc[0][i] += __shfl_xor(acc[0][i], 4);  acc[1][i] += __shfl_xor(acc[1][i], 4);
        acc[2][i] += __shfl_xor(acc[2][i], 4);  acc[3][i] += __shfl_xor(acc[3][i], 4);
        acc[0][i] += __shfl_xor(acc[0][i], 8);  acc[1][i] += __shfl_xor(acc[1][i], 8);
        acc[2][i] += __shfl_xor(acc[2][i], 8);  acc[3][i] += __shfl_xor(acc[3][i], 8);
        acc[0][i] += __shfl_xor(acc[0][i], 16); acc[1][i] += __shfl_xor(acc[1][i], 16);
        acc[2][i] += __shfl_xor(acc[2][i], 16); acc[3][i] += __shfl_xor(acc[3][i], 16);
        acc[0][i] += __shfl_xor(acc[0][i], 32); acc[1][i] += __shfl_xor(acc[1][i], 32);
        acc[2][i] += __shfl_xor(acc[2][i], 32); acc[3][i] += __shfl_xor(acc[3][i], 32);
    }
    if (p == 0) {   // lanes 0..3 (lane == d)
        float dnc[4] = {dn4.x, dn4.y, dn4.z, dn4.w};
#pragma unroll
        for (int c = 0; c < 4; c++) {
            ushort4 u;
            u.x = f2bf(dnc[c] * acc[c][0]); u.y = f2bf(dnc[c] * acc[c][1]);
            u.z = f2bf(dnc[c] * acc[c][2]); u.w = f2bf(dnc[c] * acc[c][3]);
            *(ushort4*)&sh_g[wv * 4 + c][d * 4] = u;
        }
    }
    __syncthreads();

    if (wv == 0) {
        int pcol = lane & 15, quad = lane >> 4;
        // B frags: Bcomb[k][o] = k<16 ? W2_0[k][o]-W2_1[k][o] : W2_1[k-16][o]
        bf16x8 bfrag[2];
#pragma unroll
        for (int c = 0; c < 2; c++) {
            bf16x8 f;
            if (quad < 2) {
#pragma unroll
                for (int j = 0; j < 8; j++) {
                    int k = quad * 8 + j;
                    f[j] = (short)f2bf(W2_0[k * NCLS + pcol + 16 * c] - W2_1[k * NCLS + pcol + 16 * c]);
                }
            } else {
#pragma unroll
                for (int j = 0; j < 8; j++) {
                    int k = (quad - 2) * 8 + j;
                    f[j] = (short)f2bf(W2_1[k * NCLS + pcol + 16 * c]);
                }
            }
            bfrag[c] = f;
        }
        // A frag: quads 0,1 from global h16; quads 2,3 from LDS g
        bf16x8 af;
        if (quad < 2)
            af = *(const bf16x8*)(h16 + ((long)tile * 16 + pcol) * HID + (quad & 1) * 8);
        else
            af = *(const bf16x8*)&sh_g[pcol][(quad & 1) * 8];

        f32x4 c0 = {0.f, 0.f, 0.f, 0.f}, c1 = {0.f, 0.f, 0.f, 0.f};
        c0 = __builtin_amdgcn_mfma_f32_16x16x32_bf16(af, bfrag[0], c0, 0, 0, 0);
        c1 = __builtin_amdgcn_mfma_f32_16x16x32_bf16(af, bfrag[1], c1, 0, 0, 0);

        float b2a = b2[pcol], b2b = b2[pcol + 16];
#pragma unroll
        for (int r = 0; r < 4; r++) {
            long node = (long)tile * 16 + quad * 4 + r;
            float v0 = c0[r] + b2a;
            float v1 = c1[r] + b2b;
            float m = fmaxf(v0, v1);
            m = fmaxf(m, __shfl_xor(m, 1));
            m = fmaxf(m, __shfl_xor(m, 2));
            m = fmaxf(m, __shfl_xor(m, 4));
            m = fmaxf(m, __shfl_xor(m, 8));
            float sum = __expf(v0 - m) + __expf(v1 - m);
            sum += __shfl_xor(sum, 1);
            sum += __shfl_xor(sum, 2);
            sum += __shfl_xor(sum, 4);
            sum += __shfl_xor(sum, 8);
            float ls = logf(sum);
            out[node * NCLS + pcol] = v0 - m - ls;
            out[node * NCLS + pcol + 16] = v1 - m - ls;
        }
    }
}

extern "C" void kernel_launch(void* const* d_in, const int* in_sizes, int n_in,
                              void* d_out, int out_size, void* d_ws, size_t ws_size,
                              hipStream_t stream) {
    const float* x    = (const float*)d_in[0];
    const int*   ei   = (const int*)d_in[1];
    const float* ew   = (const float*)d_in[2];
    const float* W1_0 = (const float*)d_in[3];
    const float* W1_1 = (const float*)d_in[4];
    const float* b1   = (const float*)d_in[5];
    const float* W2_0 = (const float*)d_in[6];
    const float* W2_1 = (const float*)d_in[7];
    const float* b2   = (const float*)d_in[8];
    float* out = (float*)d_out;

    const int* row = ei;
    const int* col = ei + NE;

    char* ws = (char*)d_ws;
    unsigned int* partC = (unsigned int*)ws;      ws += sizeof(int) * NE;
    int*   deg       = (int*)ws;                  ws += sizeof(int) * NN;
    int*   cursor    = (int*)ws;                  ws += sizeof(int) * NN;
    float* dsum      = (float*)ws;                ws += sizeof(float) * NN;
    int*   btot      = (int*)ws;                  ws += sizeof(int) * NBKT;
    int*   rowptr    = (int*)ws;                  ws += sizeof(int) * (NN + 4);
    float* dinv      = (float*)ws;                ws += sizeof(float) * NN;
    float* xa        = (float*)ws;                ws += sizeof(float) * NN * HID;
    unsigned short* h16 = (unsigned short*)ws;    ws += sizeof(short) * NN * HID;
    unsigned char* xb8 = (unsigned char*)ws;      ws += sizeof(char) * NN * HID;
    unsigned char* h8  = (unsigned char*)ws;      ws += sizeof(char) * NN * HID;

    k_zero<<<(NN + 255) / 256, 256, 0, stream>>>(deg, dsum, btot);
    k_hist<<<GP, 256, 0, stream>>>(row, ew, deg, dsum, btot);
    k_rowptr_proj1<<<NBKT, 256, 0, stream>>>(deg, dsum, btot, rowptr, cursor,
                                             dinv, x, W1_0, W1_1, b1, xa, xb8);
    k_scatter<<<GP, 256, 0, stream>>>(row, col, ew, cursor, partC);
    k_gather1<<<NTILE, 256, 0, stream>>>(rowptr, partC, dinv, xb8, xa, h16, h8);
    k_gather2_lsm<<<NTILE, 256, 0, stream>>>(rowptr, partC, dinv, h8, h16,
                                             W2_0, W2_1, b2, out);
}

// Round 10
// 206.659 us; speedup vs baseline: 1.9530x; 1.9530x over previous
//
#include <hip/hip_runtime.h>
#include <hip/hip_bf16.h>
#include <hip/hip_fp16.h>

// DFAChebNet forward.
//  layer: x@W0 + (agg(x)-x)@W1 + b == x@(W0-W1) + agg(x@W1) + b   (project first)
//  aggregation: CSR pull-gather; CSR built by LDS-staged counting sort.
//  R21: R20's histogram/atomic-scatter CSR build regressed 2x (k_hist = 148us
//  at VALUBusy 0.34% -- 3.2M device-scope atomics serialize; LDS-first
//  aggregation was load-bearing). Revert to R18's proven build:
//   k_zero_cur | k_partition (LDS-staged, coalesced burst writes) |
//   k_bucket_sort_proj1 (sort + fused proj1) | k_gather1 | k_gather2_lsm.
//  Attribution probe: gather1 kept in R19's block-tile 4-chain form (the
//  only non-R18 piece) to isolate which half of R19's -3.6us it caused.
//  All math orders unchanged (absmax invariant 0.125).

constexpr int NN   = 100000;
constexpr int NE   = 1600000;
constexpr int FIN  = 128;
constexpr int HID  = 16;
constexpr int NCLS = 32;

constexpr int RB    = 256;                         // rows per bucket
constexpr int NBKT  = (NN + RB - 1) / RB;          // 391
constexpr int EPB   = 4096;                        // edges per partition block
constexpr int EPT   = EPB / 256;                   // 16 edges per thread
constexpr int GP    = (NE + EPB - 1) / EPB;        // 391
constexpr int CAP   = 8192;                        // bucket slot capacity (mean 4096)
constexpr int NTILE = NN / 16;                     // 6250 tiles (exact)

typedef float f32x2 __attribute__((ext_vector_type(2)));
typedef float f32x4 __attribute__((ext_vector_type(4)));
typedef short bf16x8 __attribute__((ext_vector_type(8)));

#if defined(__has_builtin)
#if __has_builtin(__builtin_amdgcn_cvt_pk_f32_fp8)
#define HAVE_CVT_FP8 1
#endif
#endif

// fp8 e4m3fn encode (RNE, subnormals flushed to 0, clamp at 448)
static __device__ __forceinline__ unsigned int f2e4m3(float f) {
    union { float f; unsigned int u; } v; v.f = f;
    unsigned int s = (v.u >> 24) & 0x80u;
    unsigned int au = v.u & 0x7fffffffu;
    if (au > 0x43E00000u) au = 0x43E00000u;        // clamp to 448
    au += 0x7ffffu + ((au >> 20) & 1u);            // RNE into 3-bit mantissa
    int e4 = (int)(au >> 23) - 120;                // 127-7
    unsigned int m = (au >> 20) & 7u;
    unsigned int byte = (e4 <= 0) ? 0u : (((unsigned int)e4 << 3) | m);
    return s | byte;
}
// 4 packed fp8 -> acc[0..3] += w * val
static __device__ __forceinline__ void fp8x4_fma(unsigned int v, float w, float* acc) {
#ifdef HAVE_CVT_FP8
    f32x2 lo = __builtin_amdgcn_cvt_pk_f32_fp8((int)v, false);
    f32x2 hi = __builtin_amdgcn_cvt_pk_f32_fp8((int)v, true);
    acc[0] += w * lo.x; acc[1] += w * lo.y;
    acc[2] += w * hi.x; acc[3] += w * hi.y;
#else
#pragma unroll
    for (int i = 0; i < 4; i++) {
        unsigned int b = (v >> (8 * i)) & 0xffu;
        float f = __int_as_float((int)(((b & 0x80u) << 24) | ((b & 0x7fu) << 20))) * 0x1p120f;
        acc[i] += w * f;
    }
#endif
}
// bf16 RNE
static __device__ __forceinline__ unsigned short f2bf(float f) {
    union { float f; unsigned int u; } v; v.f = f;
    unsigned int r = v.u + 0x7fffu + ((v.u >> 16) & 1u);
    return (unsigned short)(r >> 16);
}
// edge record: col(17 bits) | w(15 bits = signless bf16, RNE)
static __device__ __forceinline__ unsigned int wpack(float wf) {
    unsigned int b = __float_as_uint(wf) + 0x8000u;
    return (b >> 16) & 0x7fffu;
}
static __device__ __forceinline__ float wdec(unsigned int u) {
    return __uint_as_float((u >> 17) << 16);
}

// ---- zero the bucket cursors ----
__global__ void k_zero_cur(int* __restrict__ bucketCursor) {
    int i = blockIdx.x * blockDim.x + threadIdx.x;
    if (i < NBKT) bucketCursor[i] = 0;
}

// ---- pass B (R18-verbatim): LDS-staged partition; atomic reservation into
// slotted buffer; coalesced burst write-out. ----
__global__ __launch_bounds__(256) void k_partition(
    const int* __restrict__ row, const int* __restrict__ col,
    const float* __restrict__ w, int* __restrict__ bucketCursor,
    int2* __restrict__ partS) {
    __shared__ int2 stage[EPB];              // 32KB
    __shared__ unsigned short sbkt[EPB];     // 8KB
    __shared__ int cnt[NBKT];
    __shared__ int lofs[NBKT];
    __shared__ int cursor[NBKT];
    __shared__ int gbase[NBKT];
    __shared__ int sa[512], sb[512];
    int tid = threadIdx.x;
    long ebase = (long)blockIdx.x * EPB;
    int rr[EPT]; int cc[EPT]; float wv[EPT];
#pragma unroll
    for (int i = 0; i < EPT; i++) {
        long e = ebase + i * 256 + tid;
        if (e < NE) { rr[i] = row[e]; cc[i] = col[e]; wv[i] = w[e]; }
        else rr[i] = -1;
    }
    for (int i = tid; i < NBKT; i += 256) cnt[i] = 0;
    __syncthreads();
#pragma unroll
    for (int i = 0; i < EPT; i++)
        if (rr[i] >= 0) atomicAdd(&cnt[rr[i] >> 8], 1);
    __syncthreads();
    for (int i = tid; i < 512; i += 256) sa[i] = (i < NBKT) ? cnt[i] : 0;
    __syncthreads();
    int* src = sa; int* dst = sb;
    for (int off = 1; off < 512; off <<= 1) {
        for (int i = tid; i < 512; i += 256)
            dst[i] = src[i] + ((i >= off) ? src[i - off] : 0);
        __syncthreads();
        int* t = src; src = dst; dst = t;
    }
    for (int i = tid; i < NBKT; i += 256) {
        int ex = src[i] - cnt[i];
        lofs[i] = ex;
        cursor[i] = ex;
        int go = (cnt[i] > 0) ? atomicAdd(&bucketCursor[i], cnt[i]) : 0;
        gbase[i] = i * CAP + go;
    }
    __syncthreads();
#pragma unroll
    for (int i = 0; i < EPT; i++) {
        if (rr[i] >= 0) {
            int b = rr[i] >> 8;
            int p = atomicAdd(&cursor[b], 1);
            int2 v;
            v.x = cc[i] | ((rr[i] & 255) << 17);
            v.y = __float_as_int(wv[i]);
            stage[p] = v;
            sbkt[p] = (unsigned short)b;
        }
    }
    __syncthreads();
    int total = (int)min((long)EPB, NE - ebase);
    for (int i = tid; i < total; i += 256) {
        int b = sbkt[i];
        partS[gbase[b] + (i - lofs[b])] = stage[i];
    }
}

// ---- pass C (+ fused proj1, R18-verbatim): per-bucket sort by row ->
// packed CSR, rowptr, dinv; THEN (block-local) proj1 for the block's own
// 256 rows: xa = x@(W1_0-W1_1)+b1 ; xb8 = fp8(dinv * (x@W1_1)). ----
__global__ __launch_bounds__(256) void k_bucket_sort_proj1(
    const int2* __restrict__ partS, const int* __restrict__ bucketCursor,
    unsigned int* __restrict__ partC, int* __restrict__ rowptr,
    float* __restrict__ dinv,
    const float* __restrict__ x, const float* __restrict__ W1_0,
    const float* __restrict__ W1_1, const float* __restrict__ b1,
    float* __restrict__ xa, unsigned char* __restrict__ xb8) {
    __shared__ int hist[RB];
    __shared__ int cursor[RB];
    __shared__ float dsum[RB];
    __shared__ float sh_dinv[RB];
    __shared__ int wtot[4];
    __shared__ int red[4];
    int b = blockIdx.x;
    int tid = threadIdx.x;
    int lane = tid & 63, wv = tid >> 6;
    // inline exclusive scan: start = sum_{i<b} count_i
    int partial = 0;
    for (int i = tid; i < b; i += 256) partial += bucketCursor[i];
#pragma unroll
    for (int off = 1; off < 64; off <<= 1) partial += __shfl_xor(partial, off, 64);
    if (lane == 0) red[wv] = partial;
    hist[tid] = 0;
    dsum[tid] = 0.f;
    __syncthreads();
    int start = red[0] + red[1] + red[2] + red[3];
    int count = bucketCursor[b];
    const int2* src = partS + (long)b * CAP;
    for (int i = tid; i < count; i += 256)
        atomicAdd(&hist[((unsigned)src[i].x >> 17) & 255], 1);
    __syncthreads();
    int v = hist[tid];
    int sc = v;
#pragma unroll
    for (int off = 1; off < 64; off <<= 1) {
        int up = __shfl_up(sc, off, 64);
        if (lane >= off) sc += up;
    }
    if (lane == 63) wtot[wv] = sc;
    __syncthreads();
    int add = 0;
    for (int w2 = 0; w2 < wv; w2++) add += wtot[w2];
    int ex = sc + add - v;
    int node = b * RB + tid;
    if (node <= NN) rowptr[node] = start + ex;   // node==NN -> NE (last bucket)
    cursor[tid] = ex;
    __syncthreads();
    for (int i = tid; i < count; i += 256) {
        int2 p = src[i];
        int rl = ((unsigned)p.x >> 17) & 255;
        int pos = atomicAdd(&cursor[rl], 1);
        float wf = __int_as_float(p.y);
        partC[start + pos] = ((unsigned)p.x & 0x1FFFFu) | (wpack(wf) << 17);
        atomicAdd(&dsum[rl], wf);
    }
    __syncthreads();
    {
        float dsv = dsum[tid];
        float dv = dsv > 0.f ? rsqrtf(dsv) : 0.f;
        if (node < NN) dinv[node] = dv;
        sh_dinv[tid] = dv;
    }
    __syncthreads();

    // ---- fused proj1 over this block's 16 tiles (4 per wave) ----
    {
        int pcol = lane & 15, quad = lane >> 4;
        bf16x8 bfrag[2][4];
#pragma unroll
        for (int mat = 0; mat < 2; mat++) {
            const float* W = mat ? W1_1 : W1_0;
#pragma unroll
            for (int kb = 0; kb < 4; kb++) {
                bf16x8 f;
#pragma unroll
                for (int j = 0; j < 8; j++)
                    f[j] = (short)f2bf(W[(kb * 32 + quad * 8 + j) * HID + pcol]);
                bfrag[mat][kb] = f;
            }
        }
        float b1v = b1[pcol];
#pragma unroll
        for (int i = 0; i < 4; i++) {
            int tb = wv * 4 + i;
            int wid = b * 16 + tb;
            if (wid >= NTILE) break;
            const float* xrow = x + ((long)wid * 16 + pcol) * FIN + quad * 8;
            float4 xb[8];
#pragma unroll
            for (int kb = 0; kb < 4; kb++) {
                xb[2 * kb]     = *(const float4*)(xrow + kb * 32);
                xb[2 * kb + 1] = *(const float4*)(xrow + kb * 32 + 4);
            }
            f32x4 acc0 = {0.f, 0.f, 0.f, 0.f}, acc1 = {0.f, 0.f, 0.f, 0.f};
#pragma unroll
            for (int kb = 0; kb < 4; kb++) {
                float4 a0 = xb[2 * kb], a1 = xb[2 * kb + 1];
                bf16x8 af;
                af[0] = (short)f2bf(a0.x); af[1] = (short)f2bf(a0.y);
                af[2] = (short)f2bf(a0.z); af[3] = (short)f2bf(a0.w);
                af[4] = (short)f2bf(a1.x); af[5] = (short)f2bf(a1.y);
                af[6] = (short)f2bf(a1.z); af[7] = (short)f2bf(a1.w);
                acc0 = __builtin_amdgcn_mfma_f32_16x16x32_bf16(af, bfrag[0][kb], acc0, 0, 0, 0);
                acc1 = __builtin_amdgcn_mfma_f32_16x16x32_bf16(af, bfrag[1][kb], acc1, 0, 0, 0);
            }
#pragma unroll
            for (int r = 0; r < 4; r++) {
                int lidx = tb * 16 + quad * 4 + r;          // in-block row
                long nd = (long)b * RB + lidx;
                float a0 = acc0[r], a1 = acc1[r];
                xa[nd * HID + pcol] = a0 - a1 + b1v;
                float dn = sh_dinv[lidx];
                xb8[nd * HID + pcol] = (unsigned char)f2e4m3(dn * a1);
            }
        }
    }
}

// Layer-1 gather (R19 block-tile 4-chain form -- kept as attribution probe).
// 1 block = one 16-node tile, wave wv owns nodes tile*16 + wv*4 + {0..3}.
// h16 = bf16(relu(xa + dn*agg(xb8))), h8 = fp8(dn*h).
// lane = (d = dword 0..3, p = edge parity 0..15).
__global__ __launch_bounds__(256) void k_gather1(
    const int* __restrict__ rowptr, const unsigned int* __restrict__ partC,
    const float* __restrict__ dinv, const unsigned char* __restrict__ xb8,
    const float* __restrict__ xa,
    unsigned short* __restrict__ h16, unsigned char* __restrict__ h8) {
    int tile = blockIdx.x;
    int tid = threadIdx.x;
    int lane = tid & 63, wv = tid >> 6;
    int d = lane & 3, p = lane >> 2;
    int nb = tile * 16 + wv * 4;                 // wave's first node

    int s[5];
#pragma unroll
    for (int k = 0; k < 5; k++) s[k] = rowptr[nb + k];
    float4 dn4 = *(const float4*)(dinv + nb);
    float4 xav[4];
#pragma unroll
    for (int c = 0; c < 4; c++)
        xav[c] = *(const float4*)(xa + (long)(nb + c) * HID + d * 4);

    float acc[4][4];
#pragma unroll
    for (int c = 0; c < 4; c++)
#pragma unroll
        for (int i = 0; i < 4; i++) acc[c][i] = 0.f;

    int j0 = s[0] + p, j1 = s[1] + p, j2 = s[2] + p, j3 = s[3] + p;
    int e0 = s[1], e1 = s[2], e2 = s[3], e3 = s[4];
    while ((j0 < e0) | (j1 < e1) | (j2 < e2) | (j3 < e3)) {
        if (j0 < e0) {
            unsigned int u = partC[j0];
            unsigned int v = *(const unsigned int*)(xb8 + (u & 0x1FFFF) * HID + d * 4);
            fp8x4_fma(v, wdec(u), acc[0]);
            j0 += 16;
        }
        if (j1 < e1) {
            unsigned int u = partC[j1];
            unsigned int v = *(const unsigned int*)(xb8 + (u & 0x1FFFF) * HID + d * 4);
            fp8x4_fma(v, wdec(u), acc[1]);
            j1 += 16;
        }
        if (j2 < e2) {
            unsigned int u = partC[j2];
            unsigned int v = *(const unsigned int*)(xb8 + (u & 0x1FFFF) * HID + d * 4);
            fp8x4_fma(v, wdec(u), acc[2]);
            j2 += 16;
        }
        if (j3 < e3) {
            unsigned int u = partC[j3];
            unsigned int v = *(const unsigned int*)(xb8 + (u & 0x1FFFF) * HID + d * 4);
            fp8x4_fma(v, wdec(u), acc[3]);
            j3 += 16;
        }
    }
#pragma unroll
    for (int i = 0; i < 4; i++) {
#pragma unroll
        for (int c = 0; c < 4; c++) acc[c][i] += __shfl_xor(acc[c][i], 4);
#pragma unroll
        for (int c = 0; c < 4; c++) acc[c][i] += __shfl_xor(acc[c][i], 8);
#pragma unroll
        for (int c = 0; c < 4; c++) acc[c][i] += __shfl_xor(acc[c][i], 16);
#pragma unroll
        for (int c = 0; c < 4; c++) acc[c][i] += __shfl_xor(acc[c][i], 32);
    }
    if (p == 0) {   // lanes 0..3 (lane == d)
        float dnc[4] = {dn4.x, dn4.y, dn4.z, dn4.w};
#pragma unroll
        for (int c = 0; c < 4; c++) {
            long n = nb + c;
            float h0 = fmaxf(xav[c].x + dnc[c] * acc[c][0], 0.f);
            float h1 = fmaxf(xav[c].y + dnc[c] * acc[c][1], 0.f);
            float h2 = fmaxf(xav[c].z + dnc[c] * acc[c][2], 0.f);
            float h3 = fmaxf(xav[c].w + dnc[c] * acc[c][3], 0.f);
            ushort4 u;
            u.x = f2bf(h0); u.y = f2bf(h1); u.z = f2bf(h2); u.w = f2bf(h3);
            *(ushort4*)(h16 + n * HID + d * 4) = u;
            unsigned int pk = f2e4m3(dnc[c] * h0) | (f2e4m3(dnc[c] * h1) << 8)
                            | (f2e4m3(dnc[c] * h2) << 16) | (f2e4m3(dnc[c] * h3) << 24);
            *(unsigned int*)(h8 + n * HID + d * 4) = pk;
        }
    }
}

// Layer-2 gather + final projection + log-softmax (R18-verbatim).
//  1 block = one 16-node tile. 4 waves x 4-chain interleaved gather:
//  wave wv owns nodes tile*16 + wv*4 + {0..3}; g = bf16(dn*agg(h8)) goes to
//  512B LDS. Then wave 0: v = [h16;g]@[W2_0-W2_1;W2_1] + b2 (two 16x16x32
//  bf16 MFMAs, K=32 concat) and log-softmax.
__global__ __launch_bounds__(256) void k_gather2_lsm(
    const int* __restrict__ rowptr, const unsigned int* __restrict__ partC,
    const float* __restrict__ dinv, const unsigned char* __restrict__ h8,
    const unsigned short* __restrict__ h16,
    const float* __restrict__ W2_0, const float* __restrict__ W2_1,
    const float* __restrict__ b2, float* __restrict__ out) {
    __shared__ unsigned short sh_g[16][16];     // bf16 g for the tile
    int tile = blockIdx.x;
    int tid = threadIdx.x;
    int lane = tid & 63, wv = tid >> 6;
    int d = lane & 3, p = lane >> 2;
    int nb = tile * 16 + wv * 4;                 // wave's first node

    int s[5];
#pragma unroll
    for (int k = 0; k < 5; k++) s[k] = rowptr[nb + k];
    float4 dn4 = *(const float4*)(dinv + nb);

    float acc[4][4];
#pragma unroll
    for (int c = 0; c < 4; c++)
#pragma unroll
        for (int i = 0; i < 4; i++) acc[c][i] = 0.f;

    int j0 = s[0] + p, j1 = s[1] + p, j2 = s[2] + p, j3 = s[3] + p;
    int e0 = s[1], e1 = s[2], e2 = s[3], e3 = s[4];
    while ((j0 < e0) | (j1 < e1) | (j2 < e2) | (j3 < e3)) {
        if (j0 < e0) {
            unsigned int u = partC[j0];
            unsigned int v = *(const unsigned int*)(h8 + (u & 0x1FFFF) * HID + d * 4);
            fp8x4_fma(v, wdec(u), acc[0]);
            j0 += 16;
        }
        if (j1 < e1) {
            unsigned int u = partC[j1];
            unsigned int v = *(const unsigned int*)(h8 + (u & 0x1FFFF) * HID + d * 4);
            fp8x4_fma(v, wdec(u), acc[1]);
            j1 += 16;
        }
        if (j2 < e2) {
            unsigned int u = partC[j2];
            unsigned int v = *(const unsigned int*)(h8 + (u & 0x1FFFF) * HID + d * 4);
            fp8x4_fma(v, wdec(u), acc[2]);
            j2 += 16;
        }
        if (j3 < e3) {
            unsigned int u = partC[j3];
            unsigned int v = *(const unsigned int*)(h8 + (u & 0x1FFFF) * HID + d * 4);
            fp8x4_fma(v, wdec(u), acc[3]);
            j3 += 16;
        }
    }
#pragma unroll
    for (int i = 0; i < 4; i++) {
        acc[0][i] += __shfl_xor(acc[0][i], 4);  acc[1][i] += __shfl_xor(acc[1][i], 4);
        acc[2][i] += __shfl_xor(acc[2][i], 4);  acc[3][i] += __shfl_xor(acc[3][i], 4);
        acc[0][i] += __shfl_xor(acc[0][i], 8);  acc[1][i] += __shfl_xor(acc[1][i], 8);
        acc[2][i] += __shfl_xor(acc[2][i], 8);  acc[3][i] += __shfl_xor(acc[3][i], 8);
        acc[0][i] += __shfl_xor(acc[0][i], 16); acc[1][i] += __shfl_xor(acc[1][i], 16);
        acc[2][i] += __shfl_xor(acc[2][i], 16); acc[3][i] += __shfl_xor(acc[3][i], 16);
        acc[0][i] += __shfl_xor(acc[0][i], 32); acc[1][i] += __shfl_xor(acc[1][i], 32);
        acc[2][i] += __shfl_xor(acc[2][i], 32); acc[3][i] += __shfl_xor(acc[3][i], 32);
    }
    if (p == 0) {   // lanes 0..3 (lane == d)
        float dnc[4] = {dn4.x, dn4.y, dn4.z, dn4.w};
#pragma unroll
        for (int c = 0; c < 4; c++) {
            ushort4 u;
            u.x = f2bf(dnc[c] * acc[c][0]); u.y = f2bf(dnc[c] * acc[c][1]);
            u.z = f2bf(dnc[c] * acc[c][2]); u.w = f2bf(dnc[c] * acc[c][3]);
            *(ushort4*)&sh_g[wv * 4 + c][d * 4] = u;
        }
    }
    __syncthreads();

    if (wv == 0) {
        int pcol = lane & 15, quad = lane >> 4;
        // B frags: Bcomb[k][o] = k<16 ? W2_0[k][o]-W2_1[k][o] : W2_1[k-16][o]
        bf16x8 bfrag[2];
#pragma unroll
        for (int c = 0; c < 2; c++) {
            bf16x8 f;
            if (quad < 2) {
#pragma unroll
                for (int j = 0; j < 8; j++) {
                    int k = quad * 8 + j;
                    f[j] = (short)f2bf(W2_0[k * NCLS + pcol + 16 * c] - W2_1[k * NCLS + pcol + 16 * c]);
                }
            } else {
#pragma unroll
                for (int j = 0; j < 8; j++) {
                    int k = (quad - 2) * 8 + j;
                    f[j] = (short)f2bf(W2_1[k * NCLS + pcol + 16 * c]);
                }
            }
            bfrag[c] = f;
        }
        // A frag: quads 0,1 from global h16; quads 2,3 from LDS g
        bf16x8 af;
        if (quad < 2)
            af = *(const bf16x8*)(h16 + ((long)tile * 16 + pcol) * HID + (quad & 1) * 8);
        else
            af = *(const bf16x8*)&sh_g[pcol][(quad & 1) * 8];

        f32x4 c0 = {0.f, 0.f, 0.f, 0.f}, c1 = {0.f, 0.f, 0.f, 0.f};
        c0 = __builtin_amdgcn_mfma_f32_16x16x32_bf16(af, bfrag[0], c0, 0, 0, 0);
        c1 = __builtin_amdgcn_mfma_f32_16x16x32_bf16(af, bfrag[1], c1, 0, 0, 0);

        float b2a = b2[pcol], b2b = b2[pcol + 16];
#pragma unroll
        for (int r = 0; r < 4; r++) {
            long node = (long)tile * 16 + quad * 4 + r;
            float v0 = c0[r] + b2a;
            float v1 = c1[r] + b2b;
            float m = fmaxf(v0, v1);
            m = fmaxf(m, __shfl_xor(m, 1));
            m = fmaxf(m, __shfl_xor(m, 2));
            m = fmaxf(m, __shfl_xor(m, 4));
            m = fmaxf(m, __shfl_xor(m, 8));
            float sum = __expf(v0 - m) + __expf(v1 - m);
            sum += __shfl_xor(sum, 1);
            sum += __shfl_xor(sum, 2);
            sum += __shfl_xor(sum, 4);
            sum += __shfl_xor(sum, 8);
            float ls = logf(sum);
            out[node * NCLS + pcol] = v0 - m - ls;
            out[node * NCLS + pcol + 16] = v1 - m - ls;
        }
    }
}

extern "C" void kernel_launch(void* const* d_in, const int* in_sizes, int n_in,
                              void* d_out, int out_size, void* d_ws, size_t ws_size,
                              hipStream_t stream) {
    const float* x    = (const float*)d_in[0];
    const int*   ei   = (const int*)d_in[1];
    const float* ew   = (const float*)d_in[2];
    const float* W1_0 = (const float*)d_in[3];
    const float* W1_1 = (const float*)d_in[4];
    const float* b1   = (const float*)d_in[5];
    const float* W2_0 = (const float*)d_in[6];
    const float* W2_1 = (const float*)d_in[7];
    const float* b2   = (const float*)d_in[8];
    float* out = (float*)d_out;

    const int* row = ei;
    const int* col = ei + NE;

    char* ws = (char*)d_ws;
    int2*  partS     = (int2*)ws;                 ws += sizeof(int2) * (long)NBKT * CAP;
    unsigned int* partC = (unsigned int*)ws;      ws += sizeof(int) * NE;
    int*   bucketCursor = (int*)ws;               ws += sizeof(int) * NBKT;
    int*   rowptr    = (int*)ws;                  ws += sizeof(int) * (NN + 4);
    float* dinv      = (float*)ws;                ws += sizeof(float) * NN;
    float* xa        = (float*)ws;                ws += sizeof(float) * NN * HID;
    unsigned short* h16 = (unsigned short*)ws;    ws += sizeof(short) * NN * HID;
    unsigned char* xb8 = (unsigned char*)ws;      ws += sizeof(char) * NN * HID;
    unsigned char* h8  = (unsigned char*)ws;      ws += sizeof(char) * NN * HID;

    k_zero_cur<<<(NBKT + 255) / 256, 256, 0, stream>>>(bucketCursor);
    k_partition<<<GP, 256, 0, stream>>>(row, col, ew, bucketCursor, partS);
    k_bucket_sort_proj1<<<NBKT, 256, 0, stream>>>(partS, bucketCursor, partC,
                                                  rowptr, dinv, x, W1_0, W1_1,
                                                  b1, xa, xb8);
    k_gather1<<<NTILE, 256, 0, stream>>>(rowptr, partC, dinv, xb8, xa, h16, h8);
    k_gather2_lsm<<<NTILE, 256, 0, stream>>>(rowptr, partC, dinv, h8, h16,
                                             W2_0, W2_1, b2, out);
}